// Round 12
// baseline (196.461 us; speedup 1.0000x reference)
//
#include <hip/hip_runtime.h>
#include <hip/hip_bf16.h>
#include <hip/hip_cooperative_groups.h>

namespace cg = cooperative_groups;

typedef __attribute__((ext_vector_type(8))) short short8;
typedef __attribute__((ext_vector_type(4))) short s16x4;
typedef __attribute__((ext_vector_type(4))) float f32x4;

#define S_LEN 4096
#define DM 512
#define NH 8
#define HD 64
#define NB 2

__device__ __forceinline__ ushort f2bf(float f) {
    union { float f; unsigned int i; } x; x.f = f;
    unsigned int i = x.i;
    unsigned int r = (i + 0x7fffu + ((i >> 16) & 1u)) >> 16;
    return (ushort)r;
}

__device__ __forceinline__ void gload16(const ushort* g, ushort* l) {
    __builtin_amdgcn_global_load_lds(
        (const __attribute__((address_space(1))) unsigned int*)(g),
        (__attribute__((address_space(3))) unsigned int*)(l),
        16, 0, 0);
}

__device__ __forceinline__ f32x4 mfma16(s16x4 a, s16x4 b, f32x4 c) {
#if __has_builtin(__builtin_amdgcn_mfma_f32_16x16x16bf16_1k)
    return __builtin_amdgcn_mfma_f32_16x16x16bf16_1k(a, b, c, 0, 0, 0);
#else
    f32x4 d;
    asm volatile("v_mfma_f32_16x16x16_bf16 %0, %1, %2, %3"
                 : "=v"(d) : "v"(a), "v"(b), "v"(c));
    return d;
#endif
}

// ===========================================================================
// FUSED cooperative kernel. Grid-stride over virtual tiles in every stage so
// ANY physical grid works. LDS overlay capped at 32 KB/block.
// ===========================================================================
__global__ __launch_bounds__(256) void fused_kernel(
    const float* __restrict__ x,
    const float* __restrict__ Wq, const float* __restrict__ bq,
    const float* __restrict__ Wk, const float* __restrict__ bk,
    const float* __restrict__ Wv, const float* __restrict__ bv,
    const float* __restrict__ Wo, const float* __restrict__ bo,
    float* __restrict__ Out,
    ushort* __restrict__ Xb, ushort* __restrict__ Wqb, ushort* __restrict__ Wkb,
    ushort* __restrict__ Wvb, ushort* __restrict__ Wob,
    ushort* __restrict__ Qws, ushort* __restrict__ Kws,
    ushort* __restrict__ Vtp, ushort* __restrict__ AO)
{
    __shared__ __align__(1024) ushort lds[16384];   // 32 KB overlay

    cg::grid_group grid = cg::this_grid();

    const int lane = threadIdx.x & 63;
    const int w    = threadIdx.x >> 6;
    const int lr = lane & 15;
    const int lg = lane >> 4;
    const int ldrow = lane >> 3;
    const int ldcol = (lane & 7) * 8;

    // ================= stage 0: f32 -> bf16 conversion ====================
    {
        const int stride = gridDim.x * 256;
        const int tid = blockIdx.x * 256 + threadIdx.x;
        for (int t = tid; t < 655360; t += stride) {
            const float* src; ushort* dst; size_t i;
            if (t < 524288) { src = x; dst = Xb; i = (size_t)t; }
            else {
                const int wt = t - 524288;
                const int which = wt >> 15;
                i = (size_t)(wt & 32767);
                src = (which == 0) ? Wq : (which == 1) ? Wk : (which == 2) ? Wv : Wo;
                dst = (which == 0) ? Wqb : (which == 1) ? Wkb : (which == 2) ? Wvb : Wob;
            }
            const float4* s = (const float4*)src;
            float4 a = s[i * 2], b = s[i * 2 + 1];
            short8 o;
            o[0] = (short)f2bf(a.x); o[1] = (short)f2bf(a.y);
            o[2] = (short)f2bf(a.z); o[3] = (short)f2bf(a.w);
            o[4] = (short)f2bf(b.x); o[5] = (short)f2bf(b.y);
            o[6] = (short)f2bf(b.z); o[7] = (short)f2bf(b.w);
            *(short8*)(dst + i * 8) = o;
        }
    }
    grid.sync();

    // ================= stage 1: fused QKV (64-row tiles, 1024 vtiles) =====
    {
        ushort* As  = lds;            // 64x64  = 4096
        ushort* Bsp = lds + 4096;     // 3x64x64 = 12288
        const ushort* Wm[3] = { Wqb, Wkb, Wvb };
        const float*  bm[3] = { bq, bk, bv };

        for (int vb = blockIdx.x; vb < 1024; vb += gridDim.x) {
            __syncthreads();
            const int xcd = vb & 7;
            const int idx = vb >> 3;             // 0..127
            const int tc  = idx & 7;
            const int tr  = xcd + 8 * (idx >> 3);   // 0..127
            const int c0  = tc * 64;
            const int r0  = tr * 64;

            f32x4 acc[3][4] = {};
            for (int ks = 0; ks < 8; ks++) {
                const int k0 = ks * 64;
                if (ks) __syncthreads();
                const ushort* gA = Xb + (size_t)(r0 + ldrow) * DM + k0 + ldcol;
#pragma unroll
                for (int j = 0; j < 2; j++) {
                    const int ch = w * 2 + j;
                    gload16(gA + (size_t)ch * 8 * DM, As + ch * 512);
                }
#pragma unroll
                for (int j = 0; j < 6; j++) {
                    const int q = w * 6 + j;
                    const int mat = q >> 3, ch = q & 7;
                    gload16(Wm[mat] + (size_t)(c0 + ch * 8 + ldrow) * DM + k0 + ldcol,
                            Bsp + mat * 4096 + ch * 512);
                }
                __syncthreads();

#pragma unroll
                for (int kk = 0; kk < 2; kk++) {
                    const int koff = kk * 32 + lg * 8;
                    short8 a = *(const short8*)(As + (w * 16 + lr) * 64 + koff);
#pragma unroll
                    for (int mat = 0; mat < 3; mat++)
#pragma unroll
                        for (int n = 0; n < 4; n++) {
                            short8 b = *(const short8*)(Bsp + mat * 4096 + (16 * n + lr) * 64 + koff);
                            acc[mat][n] = __builtin_amdgcn_mfma_f32_16x16x32_bf16(
                                a, b, acc[mat][n], 0, 0, 0);
                        }
                }
            }

#pragma unroll
            for (int mat = 0; mat < 3; mat++) {
#pragma unroll
                for (int n = 0; n < 4; n++) {
                    const int c = c0 + 16 * n + lr;
                    const float bb = bm[mat][c];
                    const int h = c >> 6, d = c & 63;
                    const int row0 = r0 + w * 16 + 4 * lg;
                    const int bidx = row0 >> 12;
                    const int s0 = row0 & (S_LEN - 1);
                    if (mat == 2) {
                        uint2 u;
                        u.x = (uint)f2bf(acc[2][n][0] + bb) |
                              ((uint)f2bf(acc[2][n][1] + bb) << 16);
                        u.y = (uint)f2bf(acc[2][n][2] + bb) |
                              ((uint)f2bf(acc[2][n][3] + bb) << 16);
                        *(uint2*)(Vtp + ((size_t)(bidx * NH + h) * HD + d) * S_LEN + s0) = u;
                    } else {
                        ushort* dst = (mat == 0) ? Qws : Kws;
#pragma unroll
                        for (int r = 0; r < 4; r++)
                            dst[((size_t)(bidx * NH + h) * S_LEN + s0 + r) * HD + d] =
                                f2bf(acc[mat][n][r] + bb);
                    }
                }
            }
        }
    }
    grid.sync();

    // ================= stage 2: attention (sequential K/V in 24 KB) =======
    {
        ushort* KVs = lds;   // 12288 ushorts; K then V (K dead after QK^T)

        for (int vb = blockIdx.x; vb < 1024; vb += gridDim.x) {
            __syncthreads();
            const int xcd = vb & 7;
            const int idx = vb >> 3;
            const int bh  = xcd * 2 + (idx >> 6);
            const int qb  = idx & 63;

            const ushort* Qh = Qws + (size_t)bh * S_LEN * HD;
            const ushort* Kh = Kws + (size_t)bh * S_LEN * HD;
            const ushort* Vh = Vtp + (size_t)bh * HD * S_LEN;

            const int q0 = qb * 64 + w * 16;
            const int kstart = qb * 64 - 64;

            // stage K [192][64] swizzled
#pragma unroll
            for (int i = 0; i < 6; i++) {
                const int sb = w * 384 + i * 64;
                const int s = sb + lane;
                const int row = s >> 3;
                const int g = (s & 7) ^ (row & 7);
                int rg = kstart + row;
                rg = (rg < 0) ? 0 : (rg >= S_LEN ? S_LEN - 1 : rg);
                gload16(Kh + (size_t)rg * HD + g * 8, KVs + sb * 8);
            }
            short8 qa[2];
#pragma unroll
            for (int kk = 0; kk < 2; kk++)
                qa[kk] = *(const short8*)(Qh + (size_t)(q0 + lr) * HD + kk * 32 + lg * 8);

            __syncthreads();

            const int swz = (lr & 7) << 3;

            f32x4 sc[12];
#pragma unroll
            for (int ct = 0; ct < 12; ct++) {
                sc[ct] = f32x4{0.f, 0.f, 0.f, 0.f};
                const int base = (ct * 16 + lr) * 64;
                short8 kb0 = *(const short8*)(KVs + (base + ((0  + lg * 8) ^ swz)));
                short8 kb1 = *(const short8*)(KVs + (base + ((32 + lg * 8) ^ swz)));
                sc[ct] = __builtin_amdgcn_mfma_f32_16x16x32_bf16(kb0, qa[0], sc[ct], 0, 0, 0);
                sc[ct] = __builtin_amdgcn_mfma_f32_16x16x32_bf16(kb1, qa[1], sc[ct], 0, 0, 0);
            }

            __syncthreads();   // all K reads done -> safe to overwrite with V

            // stage V^T [64][192] swizzled (latency overlaps softmax below)
#pragma unroll
            for (int i = 0; i < 6; i++) {
                const int sb = w * 384 + i * 64;
                const int s = sb + lane;
                const int row = s / 24;
                const int sr = s - row * 24;
                const int cr = sr ^ (row & 7);
                int cg = kstart + cr * 8;
                cg = (cg < 0) ? 0 : (cg > S_LEN - 8 ? S_LEN - 8 : cg);
                gload16(Vh + (size_t)row * S_LEN + cg, KVs + sb * 8);
            }

            // softmax: lane-local over 48 keys + 2 shfls (register-only)
            const float scale2 = 0.18033688f;   // (1/8) * log2(e)
            const int qi = q0 + lr;
            float sum = 0.f;
#pragma unroll
            for (int ct = 0; ct < 12; ct++) {
#pragma unroll
                for (int r = 0; r < 4; r++) {
                    const int j = kstart + ct * 16 + 4 * lg + r;
                    const bool valid = (j >= 0) && (j < S_LEN) && (qi - j <= 64) && (j - qi <= 64);
                    const float p = valid ? exp2f(sc[ct][r] * scale2) : 0.f;
                    sc[ct][r] = p;
                    sum += p;
                }
            }
            sum += __shfl_xor(sum, 16);
            sum += __shfl_xor(sum, 32);
            const float inv = 1.0f / sum;

            s16x4 pb[12];
#pragma unroll
            for (int ct = 0; ct < 12; ct++) {
                pb[ct][0] = (short)f2bf(sc[ct][0]);
                pb[ct][1] = (short)f2bf(sc[ct][1]);
                pb[ct][2] = (short)f2bf(sc[ct][2]);
                pb[ct][3] = (short)f2bf(sc[ct][3]);
            }

            __syncthreads();   // V staged

            f32x4 po[4] = {};
#pragma unroll
            for (int ct = 0; ct < 12; ct++) {
                const int k0 = ct * 16 + 4 * lg;
                const int sub = k0 & 7;
                const int ch = k0 >> 3;
#pragma unroll
                for (int n = 0; n < 4; n++) {
                    const int d = 16 * n + lr;
                    s16x4 va = *(const s16x4*)(KVs + d * 192 + 8 * (ch ^ (lr & 7)) + sub);
                    po[n] = mfma16(va, pb[ct], po[n]);
                }
            }

            const int b = bh >> 3, h = bh & 7;
            ushort* aorow = AO + ((size_t)(b * S_LEN + q0 + lr)) * DM + h * HD;
#pragma unroll
            for (int n = 0; n < 4; n++) {
                uint2 u;
                u.x = (uint)f2bf(po[n][0] * inv) | ((uint)f2bf(po[n][1] * inv) << 16);
                u.y = (uint)f2bf(po[n][2] * inv) | ((uint)f2bf(po[n][3] * inv) << 16);
                *(uint2*)(aorow + 16 * n + 4 * lg) = u;
            }
        }
    }
    grid.sync();

    // ================= stage 3: output projection (512 vtiles) ============
    {
        ushort* As = lds;            // 64x64 = 4096
        ushort* Bs = lds + 4096;     // 128x64 = 8192

        for (int vb = blockIdx.x; vb < 512; vb += gridDim.x) {
            __syncthreads();
            const int xcd = vb & 7;
            const int idx = vb >> 3;
            const int tr  = xcd + 8 * (idx >> 2);
            const int tc  = idx & 3;
            const int c0  = tc * 128;
            const int r0  = tr * 64;
            const int wr = w >> 1, wc = w & 1;

            f32x4 acc[2][4] = {};
            for (int ks = 0; ks < 8; ks++) {
                const int k0 = ks * 64;
                if (ks) __syncthreads();
                const ushort* gA = AO + (size_t)(r0 + ldrow) * DM + k0 + ldcol;
                const ushort* gB = Wob + (size_t)(c0 + ldrow) * DM + k0 + ldcol;
#pragma unroll
                for (int j = 0; j < 2; j++) {
                    const int ch = w * 2 + j;
                    gload16(gA + (size_t)ch * 8 * DM, As + ch * 512);
                }
#pragma unroll
                for (int j = 0; j < 4; j++) {
                    const int ch = w * 4 + j;
                    gload16(gB + (size_t)ch * 8 * DM, Bs + ch * 512);
                }
                __syncthreads();

#pragma unroll
                for (int kk = 0; kk < 2; kk++) {
                    const int koff = kk * 32 + lg * 8;
                    short8 a[2], b[4];
#pragma unroll
                    for (int m = 0; m < 2; m++)
                        a[m] = *(const short8*)(As + (wr * 32 + 16 * m + lr) * 64 + koff);
#pragma unroll
                    for (int n = 0; n < 4; n++)
                        b[n] = *(const short8*)(Bs + (wc * 64 + 16 * n + lr) * 64 + koff);
#pragma unroll
                    for (int m = 0; m < 2; m++)
#pragma unroll
                        for (int n = 0; n < 4; n++)
                            acc[m][n] = __builtin_amdgcn_mfma_f32_16x16x32_bf16(a[m], b[n], acc[m][n], 0, 0, 0);
                }
            }

#pragma unroll
            for (int n = 0; n < 4; n++) {
                const int c = c0 + wc * 64 + 16 * n + lr;
                const float bb = bo[c];
#pragma unroll
                for (int m = 0; m < 2; m++) {
#pragma unroll
                    for (int r = 0; r < 4; r++) {
                        const int row = r0 + wr * 32 + 16 * m + 4 * lg + r;
                        Out[(size_t)row * DM + c] = acc[m][n][r] + bb;
                    }
                }
            }
        }
    }
}

// ===========================================================================
// FALLBACK path: round-10 four-kernel pipeline (proven 58.3 us).
// ===========================================================================
__global__ __launch_bounds__(256) void cvt_all_kernel(
    const float* __restrict__ x,
    const float* __restrict__ s0, const float* __restrict__ s1,
    const float* __restrict__ s2, const float* __restrict__ s3,
    ushort* __restrict__ xb,
    ushort* __restrict__ t0, ushort* __restrict__ t1,
    ushort* __restrict__ t2, ushort* __restrict__ t3)
{
    const float* src;
    ushort* dst;
    size_t i;
    if (blockIdx.x < 2048) {
        src = x; dst = xb;
        i = (size_t)blockIdx.x * 256 + threadIdx.x;
    } else {
        const int wb = blockIdx.x - 2048;
        const int which = wb >> 7;
        src = (which == 0) ? s0 : (which == 1) ? s1 : (which == 2) ? s2 : s3;
        dst = (which == 0) ? t0 : (which == 1) ? t1 : (which == 2) ? t2 : t3;
        i = (size_t)(wb & 127) * 256 + threadIdx.x;
    }
    const float4* s = (const float4*)src;
    float4 a = s[i * 2], b = s[i * 2 + 1];
    short8 o;
    o[0] = (short)f2bf(a.x); o[1] = (short)f2bf(a.y);
    o[2] = (short)f2bf(a.z); o[3] = (short)f2bf(a.w);
    o[4] = (short)f2bf(b.x); o[5] = (short)f2bf(b.y);
    o[6] = (short)f2bf(b.z); o[7] = (short)f2bf(b.w);
    *(short8*)(dst + i * 8) = o;
}

__global__ __launch_bounds__(256) void qkv_proj_kernel(
    const ushort* __restrict__ X,
    const ushort* __restrict__ Wq, const float* __restrict__ bq,
    const ushort* __restrict__ Wk, const float* __restrict__ bk,
    const ushort* __restrict__ Wv, const float* __restrict__ bv,
    ushort* __restrict__ Qws, ushort* __restrict__ Kws, ushort* __restrict__ Vt)
{
    __shared__ __align__(1024) ushort As[128 * 64];
    __shared__ __align__(1024) ushort Bs[3][64 * 64];

    const int lane = threadIdx.x & 63;
    const int w    = threadIdx.x >> 6;
    const int xcd  = blockIdx.x & 7;
    const int idx  = blockIdx.x >> 3;
    const int tc   = idx & 7;
    const int tr   = xcd + 8 * (idx >> 3);
    const int c0   = tc * 64;
    const int r0   = tr * 128;

    const ushort* Wm[3] = { Wq, Wk, Wv };
    const float*  bm[3] = { bq, bk, bv };

    const int lr = lane & 15;
    const int lg = lane >> 4;
    const int ldrow = lane >> 3;
    const int ldcol = (lane & 7) * 8;

    f32x4 acc[3][2][4] = {};
    for (int ks = 0; ks < 8; ks++) {
        const int k0 = ks * 64;
        if (ks) __syncthreads();
        const ushort* gA = X + (size_t)(r0 + ldrow) * DM + k0 + ldcol;
#pragma unroll
        for (int j = 0; j < 4; j++) {
            const int ch = w * 4 + j;
            gload16(gA + (size_t)ch * 8 * DM, As + ch * 512);
        }
#pragma unroll
        for (int j = 0; j < 6; j++) {
            const int q = w * 6 + j;
            const int mat = q >> 3, ch = q & 7;
            gload16(Wm[mat] + (size_t)(c0 + ch * 8 + ldrow) * DM + k0 + ldcol,
                    &Bs[mat][ch * 512]);
        }
        __syncthreads();

#pragma unroll
        for (int kk = 0; kk < 2; kk++) {
            const int koff = kk * 32 + lg * 8;
            short8 a[2], b[3][4];
#pragma unroll
            for (int m = 0; m < 2; m++)
                a[m] = *(const short8*)(As + (w * 32 + 16 * m + lr) * 64 + koff);
#pragma unroll
            for (int mat = 0; mat < 3; mat++)
#pragma unroll
                for (int n = 0; n < 4; n++)
                    b[mat][n] = *(const short8*)(&Bs[mat][(16 * n + lr) * 64 + koff]);
#pragma unroll
            for (int mat = 0; mat < 3; mat++)
#pragma unroll
                for (int m = 0; m < 2; m++)
#pragma unroll
                    for (int n = 0; n < 4; n++)
                        acc[mat][m][n] = __builtin_amdgcn_mfma_f32_16x16x32_bf16(
                            a[m], b[mat][n], acc[mat][m][n], 0, 0, 0);
        }
    }

#pragma unroll
    for (int mat = 0; mat < 3; mat++) {
#pragma unroll
        for (int n = 0; n < 4; n++) {
            const int c = c0 + 16 * n + lr;
            const float bb = bm[mat][c];
            const int h = c >> 6, d = c & 63;
#pragma unroll
            for (int m = 0; m < 2; m++) {
                const int row0 = r0 + w * 32 + 16 * m + 4 * lg;
                const int bidx = row0 >> 12;
                const int s0 = row0 & (S_LEN - 1);
                if (mat == 2) {
                    uint2 u;
                    u.x = (uint)f2bf(acc[2][m][n][0] + bb) |
                          ((uint)f2bf(acc[2][m][n][1] + bb) << 16);
                    u.y = (uint)f2bf(acc[2][m][n][2] + bb) |
                          ((uint)f2bf(acc[2][m][n][3] + bb) << 16);
                    *(uint2*)(Vt + ((size_t)(bidx * NH + h) * HD + d) * S_LEN + s0) = u;
                } else {
                    ushort* dst = (mat == 0) ? Qws : Kws;
#pragma unroll
                    for (int r = 0; r < 4; r++)
                        dst[((size_t)(bidx * NH + h) * S_LEN + s0 + r) * HD + d] =
                            f2bf(acc[mat][m][n][r] + bb);
                }
            }
        }
    }
}

__global__ __launch_bounds__(256) void attn_kernel(
    const ushort* __restrict__ Qws, const ushort* __restrict__ Kws,
    const ushort* __restrict__ Vt, ushort* __restrict__ AO)
{
    __shared__ __align__(1024) ushort Ks[192 * 64];
    __shared__ __align__(1024) ushort Vs[64 * 192];

    const int x   = blockIdx.x;
    const int xcd = x & 7;
    const int idx = x >> 3;
    const int bh  = xcd * 2 + (idx >> 6);
    const int qb  = idx & 63;
    const int w   = threadIdx.x >> 6;
    const int lane = threadIdx.x & 63;
    const int lr = lane & 15;
    const int lg = lane >> 4;

    const ushort* Qh = Qws + (size_t)bh * S_LEN * HD;
    const ushort* Kh = Kws + (size_t)bh * S_LEN * HD;
    const ushort* Vh = Vt  + (size_t)bh * HD * S_LEN;

    const int q0 = qb * 64 + w * 16;
    const int kstart = qb * 64 - 64;

#pragma unroll
    for (int i = 0; i < 6; i++) {
        const int sb = w * 384 + i * 64;
        const int s = sb + lane;
        const int row = s >> 3;
        const int g = (s & 7) ^ (row & 7);
        int rg = kstart + row;
        rg = (rg < 0) ? 0 : (rg >= S_LEN ? S_LEN - 1 : rg);
        gload16(Kh + (size_t)rg * HD + g * 8, Ks + sb * 8);
    }
#pragma unroll
    for (int i = 0; i < 6; i++) {
        const int sb = w * 384 + i * 64;
        const int s = sb + lane;
        const int row = s / 24;
        const int sr = s - row * 24;
        const int cr = sr ^ (row & 7);
        int cg = kstart + cr * 8;
        cg = (cg < 0) ? 0 : (cg > S_LEN - 8 ? S_LEN - 8 : cg);
        gload16(Vh + (size_t)row * S_LEN + cg, Vs + sb * 8);
    }

    short8 qa[2];
#pragma unroll
    for (int kk = 0; kk < 2; kk++)
        qa[kk] = *(const short8*)(Qh + (size_t)(q0 + lr) * HD + kk * 32 + lg * 8);

    __syncthreads();

    const int swz = (lr & 7) << 3;

    f32x4 sc[12];
#pragma unroll
    for (int ct = 0; ct < 12; ct++) {
        sc[ct] = f32x4{0.f, 0.f, 0.f, 0.f};
        const int base = (ct * 16 + lr) * 64;
        short8 kb0 = *(const short8*)(Ks + (base + ((0  + lg * 8) ^ swz)));
        short8 kb1 = *(const short8*)(Ks + (base + ((32 + lg * 8) ^ swz)));
        sc[ct] = __builtin_amdgcn_mfma_f32_16x16x32_bf16(kb0, qa[0], sc[ct], 0, 0, 0);
        sc[ct] = __builtin_amdgcn_mfma_f32_16x16x32_bf16(kb1, qa[1], sc[ct], 0, 0, 0);
    }

    const float scale2 = 0.18033688f;
    const int qi = q0 + lr;
    float sum = 0.f;
#pragma unroll
    for (int ct = 0; ct < 12; ct++) {
#pragma unroll
        for (int r = 0; r < 4; r++) {
            const int j = kstart + ct * 16 + 4 * lg + r;
            const bool valid = (j >= 0) && (j < S_LEN) && (qi - j <= 64) && (j - qi <= 64);
            const float p = valid ? exp2f(sc[ct][r] * scale2) : 0.f;
            sc[ct][r] = p;
            sum += p;
        }
    }
    sum += __shfl_xor(sum, 16);
    sum += __shfl_xor(sum, 32);
    const float inv = 1.0f / sum;

    s16x4 pb[12];
#pragma unroll
    for (int ct = 0; ct < 12; ct++) {
        pb[ct][0] = (short)f2bf(sc[ct][0]);
        pb[ct][1] = (short)f2bf(sc[ct][1]);
        pb[ct][2] = (short)f2bf(sc[ct][2]);
        pb[ct][3] = (short)f2bf(sc[ct][3]);
    }

    f32x4 po[4] = {};
#pragma unroll
    for (int ct = 0; ct < 12; ct++) {
        const int k0 = ct * 16 + 4 * lg;
        const int sub = k0 & 7;
        const int ch = k0 >> 3;
#pragma unroll
        for (int n = 0; n < 4; n++) {
            const int d = 16 * n + lr;
            s16x4 va = *(const s16x4*)(Vs + d * 192 + 8 * (ch ^ (lr & 7)) + sub);
            po[n] = mfma16(va, pb[ct], po[n]);
        }
    }

    const int b = bh >> 3, h = bh & 7;
    ushort* aorow = AO + ((size_t)(b * S_LEN + q0 + lr)) * DM + h * HD;
#pragma unroll
    for (int n = 0; n < 4; n++) {
        uint2 u;
        u.x = (uint)f2bf(po[n][0] * inv) | ((uint)f2bf(po[n][1] * inv) << 16);
        u.y = (uint)f2bf(po[n][2] * inv) | ((uint)f2bf(po[n][3] * inv) << 16);
        *(uint2*)(aorow + 16 * n + 4 * lg) = u;
    }
}

__global__ __launch_bounds__(256) void out_proj_kernel(
    const ushort* __restrict__ AO, const ushort* __restrict__ Wo,
    const float* __restrict__ bo, float* __restrict__ Out)
{
    __shared__ __align__(1024) ushort As[64 * 64];
    __shared__ __align__(1024) ushort Bs[128 * 64];

    const int lane = threadIdx.x & 63;
    const int w    = threadIdx.x >> 6;
    const int xcd  = blockIdx.x & 7;
    const int idx  = blockIdx.x >> 3;
    const int tr   = xcd + 8 * (idx >> 2);
    const int tc   = idx & 3;
    const int c0   = tc * 128;
    const int r0   = tr * 64;
    const int lr = lane & 15;
    const int lg = lane >> 4;
    const int wr = w >> 1, wc = w & 1;
    const int ldrow = lane >> 3;
    const int ldcol = (lane & 7) * 8;

    f32x4 acc[2][4] = {};
    for (int ks = 0; ks < 8; ks++) {
        const int k0 = ks * 64;
        if (ks) __syncthreads();
        const ushort* gA = AO + (size_t)(r0 + ldrow) * DM + k0 + ldcol;
        const ushort* gB = Wo + (size_t)(c0 + ldrow) * DM + k0 + ldcol;
#pragma unroll
        for (int j = 0; j < 2; j++) {
            const int ch = w * 2 + j;
            gload16(gA + (size_t)ch * 8 * DM, As + ch * 512);
        }
#pragma unroll
        for (int j = 0; j < 4; j++) {
            const int ch = w * 4 + j;
            gload16(gB + (size_t)ch * 8 * DM, Bs + ch * 512);
        }
        __syncthreads();

#pragma unroll
        for (int kk = 0; kk < 2; kk++) {
            const int koff = kk * 32 + lg * 8;
            short8 a[2], b[4];
#pragma unroll
            for (int m = 0; m < 2; m++)
                a[m] = *(const short8*)(As + (wr * 32 + 16 * m + lr) * 64 + koff);
#pragma unroll
            for (int n = 0; n < 4; n++)
                b[n] = *(const short8*)(Bs + (wc * 64 + 16 * n + lr) * 64 + koff);
#pragma unroll
            for (int m = 0; m < 2; m++)
#pragma unroll
                for (int n = 0; n < 4; n++)
                    acc[m][n] = __builtin_amdgcn_mfma_f32_16x16x32_bf16(a[m], b[n], acc[m][n], 0, 0, 0);
        }
    }

#pragma unroll
    for (int n = 0; n < 4; n++) {
        const int c = c0 + wc * 64 + 16 * n + lr;
        const float bb = bo[c];
#pragma unroll
        for (int m = 0; m < 2; m++) {
#pragma unroll
            for (int r = 0; r < 4; r++) {
                const int row = r0 + wr * 32 + 16 * m + 4 * lg + r;
                Out[(size_t)row * DM + c] = acc[m][n][r] + bb;
            }
        }
    }
}

extern "C" void kernel_launch(void* const* d_in, const int* in_sizes, int n_in,
                              void* d_out, int out_size, void* d_ws, size_t ws_size,
                              hipStream_t stream) {
    const float* x  = (const float*)d_in[0];
    const float* Wq = (const float*)d_in[1];
    const float* bq = (const float*)d_in[2];
    const float* Wk = (const float*)d_in[3];
    const float* bk = (const float*)d_in[4];
    const float* Wv = (const float*)d_in[5];
    const float* bv = (const float*)d_in[6];
    const float* Wo = (const float*)d_in[7];
    const float* bo = (const float*)d_in[8];
    float* out = (float*)d_out;

    const size_t XE = (size_t)NB * S_LEN * DM;   // 4,194,304
    const size_t WE = (size_t)DM * DM;           // 262,144

    ushort* Xb  = (ushort*)d_ws;
    ushort* Wqb = Xb + XE;
    ushort* Wkb = Wqb + WE;
    ushort* Wvb = Wkb + WE;
    ushort* Wob = Wvb + WE;
    ushort* Qws = Wob + WE;
    ushort* Kws = Qws + XE;
    ushort* Vt  = Kws + XE;
    ushort* AO  = Vt + XE;

    // --- capture-safe host-side queries (deterministic on a given device) ---
    int dev = 0;
    hipGetDevice(&dev);
    int coop = 0;
    hipDeviceGetAttribute(&coop, hipDeviceAttributeCooperativeLaunch, dev);
    int nCU = 0;
    hipDeviceGetAttribute(&nCU, hipDeviceAttributeMultiprocessorCount, dev);
    int maxBlk = 0;
    hipOccupancyMaxActiveBlocksPerMultiprocessor(&maxBlk, (const void*)fused_kernel, 256, 0);

    if (coop && maxBlk >= 1 && nCU >= 8) {
        int grid = maxBlk * nCU;
        if (grid > 512) grid = 512;
        const float *xa = x, *wqa = Wq, *bqa = bq, *wka = Wk, *bka = bk,
                    *wva = Wv, *bva = bv, *woa = Wo, *boa = bo;
        float* outa = out;
        ushort *Xba = Xb, *Wqba = Wqb, *Wkba = Wkb, *Wvba = Wvb, *Woba = Wob,
               *Qwsa = Qws, *Kwsa = Kws, *Vta = Vt, *AOa = AO;
        void* args[] = {
            (void*)&xa, (void*)&wqa, (void*)&bqa, (void*)&wka, (void*)&bka,
            (void*)&wva, (void*)&bva, (void*)&woa, (void*)&boa, (void*)&outa,
            (void*)&Xba, (void*)&Wqba, (void*)&Wkba, (void*)&Wvba, (void*)&Woba,
            (void*)&Qwsa, (void*)&Kwsa, (void*)&Vta, (void*)&AOa
        };
        hipError_t err = hipLaunchCooperativeKernel(
            (const void*)fused_kernel, dim3(grid), dim3(256), args, 0, stream);
        if (err == hipSuccess) return;
    }

    // --- fallback: proven 4-kernel pipeline ---
    cvt_all_kernel<<<2560, 256, 0, stream>>>(x, Wq, Wk, Wv, Wo, Xb, Wqb, Wkb, Wvb, Wob);
    qkv_proj_kernel<<<512, 256, 0, stream>>>(Xb, Wqb, bq, Wkb, bk, Wvb, bv, Qws, Kws, Vt);
    attn_kernel<<<1024, 256, 0, stream>>>(Qws, Kws, Vt, AO);
    out_proj_kernel<<<512, 256, 0, stream>>>(AO, Wob, bo, out);
}

// Round 13
// 57.399 us; speedup vs baseline: 3.4227x; 3.4227x over previous
//
#include <hip/hip_runtime.h>
#include <hip/hip_bf16.h>

typedef __attribute__((ext_vector_type(8))) short short8;
typedef __attribute__((ext_vector_type(4))) short s16x4;
typedef __attribute__((ext_vector_type(4))) float f32x4;

#define S_LEN 4096
#define DM 512
#define NH 8
#define HD 64
#define NB 2

__device__ __forceinline__ ushort f2bf(float f) {
    union { float f; unsigned int i; } x; x.f = f;
    unsigned int i = x.i;
    unsigned int r = (i + 0x7fffu + ((i >> 16) & 1u)) >> 16;
    return (ushort)r;
}

__device__ __forceinline__ void gload16(const ushort* g, ushort* l) {
    __builtin_amdgcn_global_load_lds(
        (const __attribute__((address_space(1))) unsigned int*)(g),
        (__attribute__((address_space(3))) unsigned int*)(l),
        16, 0, 0);
}

__device__ __forceinline__ f32x4 mfma16(s16x4 a, s16x4 b, f32x4 c) {
#if __has_builtin(__builtin_amdgcn_mfma_f32_16x16x16bf16_1k)
    return __builtin_amdgcn_mfma_f32_16x16x16bf16_1k(a, b, c, 0, 0, 0);
#else
    f32x4 d;
    asm volatile("v_mfma_f32_16x16x16_bf16 %0, %1, %2, %3"
                 : "=v"(d) : "v"(a), "v"(b), "v"(c));
    return d;
#endif
}

// ---------------------------------------------------------------------------
// fused f32 -> bf16 conversion: blocks [0,2048) convert X, [2048,2560) weights
// ---------------------------------------------------------------------------
__global__ __launch_bounds__(256) void cvt_all_kernel(
    const float* __restrict__ x,
    const float* __restrict__ s0, const float* __restrict__ s1,
    const float* __restrict__ s2, const float* __restrict__ s3,
    ushort* __restrict__ xb,
    ushort* __restrict__ t0, ushort* __restrict__ t1,
    ushort* __restrict__ t2, ushort* __restrict__ t3)
{
    const float* src;
    ushort* dst;
    size_t i;
    if (blockIdx.x < 2048) {
        src = x; dst = xb;
        i = (size_t)blockIdx.x * 256 + threadIdx.x;
    } else {
        const int wb = blockIdx.x - 2048;
        const int which = wb >> 7;
        src = (which == 0) ? s0 : (which == 1) ? s1 : (which == 2) ? s2 : s3;
        dst = (which == 0) ? t0 : (which == 1) ? t1 : (which == 2) ? t2 : t3;
        i = (size_t)(wb & 127) * 256 + threadIdx.x;
    }
    const float4* s = (const float4*)src;
    float4 a = s[i * 2], b = s[i * 2 + 1];
    short8 o;
    o[0] = (short)f2bf(a.x); o[1] = (short)f2bf(a.y);
    o[2] = (short)f2bf(a.z); o[3] = (short)f2bf(a.w);
    o[4] = (short)f2bf(b.x); o[5] = (short)f2bf(b.y);
    o[6] = (short)f2bf(b.z); o[7] = (short)f2bf(b.w);
    *(short8*)(dst + i * 8) = o;
}

// ---------------------------------------------------------------------------
// Fused QKV projection (round-10): 128-row x 64-col tile of ALL THREE
// outputs. Grid 512 = 64 tr x 8 tc, XCD-swizzled. 48 MFMA/wave/K-step.
// Q,K out [B][H][S][HD]; V out transposed [B][H][HD][S].
// ---------------------------------------------------------------------------
__global__ __launch_bounds__(256) void qkv_proj_kernel(
    const ushort* __restrict__ X,
    const ushort* __restrict__ Wq, const float* __restrict__ bq,
    const ushort* __restrict__ Wk, const float* __restrict__ bk,
    const ushort* __restrict__ Wv, const float* __restrict__ bv,
    ushort* __restrict__ Qws, ushort* __restrict__ Kws, ushort* __restrict__ Vt)
{
    __shared__ __align__(1024) ushort As[128 * 64];
    __shared__ __align__(1024) ushort Bs[3][64 * 64];

    const int lane = threadIdx.x & 63;
    const int w    = threadIdx.x >> 6;
    const int xcd  = blockIdx.x & 7;
    const int idx  = blockIdx.x >> 3;
    const int tc   = idx & 7;
    const int tr   = xcd + 8 * (idx >> 3);
    const int c0   = tc * 64;
    const int r0   = tr * 128;

    const ushort* Wm[3] = { Wq, Wk, Wv };
    const float*  bm[3] = { bq, bk, bv };

    const int lr = lane & 15;
    const int lg = lane >> 4;
    const int ldrow = lane >> 3;
    const int ldcol = (lane & 7) * 8;

    f32x4 acc[3][2][4] = {};
    for (int ks = 0; ks < 8; ks++) {
        const int k0 = ks * 64;
        if (ks) __syncthreads();
        const ushort* gA = X + (size_t)(r0 + ldrow) * DM + k0 + ldcol;
#pragma unroll
        for (int j = 0; j < 4; j++) {
            const int ch = w * 4 + j;
            gload16(gA + (size_t)ch * 8 * DM, As + ch * 512);
        }
#pragma unroll
        for (int j = 0; j < 6; j++) {
            const int q = w * 6 + j;
            const int mat = q >> 3, ch = q & 7;
            gload16(Wm[mat] + (size_t)(c0 + ch * 8 + ldrow) * DM + k0 + ldcol,
                    &Bs[mat][ch * 512]);
        }
        __syncthreads();

#pragma unroll
        for (int kk = 0; kk < 2; kk++) {
            const int koff = kk * 32 + lg * 8;
            short8 a[2], b[3][4];
#pragma unroll
            for (int m = 0; m < 2; m++)
                a[m] = *(const short8*)(As + (w * 32 + 16 * m + lr) * 64 + koff);
#pragma unroll
            for (int mat = 0; mat < 3; mat++)
#pragma unroll
                for (int n = 0; n < 4; n++)
                    b[mat][n] = *(const short8*)(&Bs[mat][(16 * n + lr) * 64 + koff]);
#pragma unroll
            for (int mat = 0; mat < 3; mat++)
#pragma unroll
                for (int m = 0; m < 2; m++)
#pragma unroll
                    for (int n = 0; n < 4; n++)
                        acc[mat][m][n] = __builtin_amdgcn_mfma_f32_16x16x32_bf16(
                            a[m], b[mat][n], acc[mat][m][n], 0, 0, 0);
        }
    }

#pragma unroll
    for (int mat = 0; mat < 3; mat++) {
#pragma unroll
        for (int n = 0; n < 4; n++) {
            const int c = c0 + 16 * n + lr;
            const float bb = bm[mat][c];
            const int h = c >> 6, d = c & 63;
#pragma unroll
            for (int m = 0; m < 2; m++) {
                const int row0 = r0 + w * 32 + 16 * m + 4 * lg;
                const int bidx = row0 >> 12;
                const int s0 = row0 & (S_LEN - 1);
                if (mat == 2) {
                    uint2 u;
                    u.x = (uint)f2bf(acc[2][m][n][0] + bb) |
                          ((uint)f2bf(acc[2][m][n][1] + bb) << 16);
                    u.y = (uint)f2bf(acc[2][m][n][2] + bb) |
                          ((uint)f2bf(acc[2][m][n][3] + bb) << 16);
                    *(uint2*)(Vt + ((size_t)(bidx * NH + h) * HD + d) * S_LEN + s0) = u;
                } else {
                    ushort* dst = (mat == 0) ? Qws : Kws;
#pragma unroll
                    for (int r = 0; r < 4; r++)
                        dst[((size_t)(bidx * NH + h) * S_LEN + s0 + r) * HD + d] =
                            f2bf(acc[mat][m][n][r] + bb);
                }
            }
        }
    }
}

// ---------------------------------------------------------------------------
// Sliding-window attention with SPLIT staging barriers:
//   issue K + Q -> barrier (K ready) -> issue V async -> QK^T -> softmax/pack
//   (V latency hides here) -> barrier (V ready) -> PV -> store.
// Swapped-operand QK^T, lane-local softmax, no P LDS (round-8 structure).
// ---------------------------------------------------------------------------
__global__ __launch_bounds__(256) void attn_kernel(
    const ushort* __restrict__ Qws, const ushort* __restrict__ Kws,
    const ushort* __restrict__ Vt, ushort* __restrict__ AO)
{
    __shared__ __align__(1024) ushort Ks[192 * 64];
    __shared__ __align__(1024) ushort Vs[64 * 192];

    const int x   = blockIdx.x;
    const int xcd = x & 7;
    const int idx = x >> 3;
    const int bh  = xcd * 2 + (idx >> 6);
    const int qb  = idx & 63;
    const int w   = threadIdx.x >> 6;
    const int lane = threadIdx.x & 63;
    const int lr = lane & 15;
    const int lg = lane >> 4;

    const ushort* Qh = Qws + (size_t)bh * S_LEN * HD;
    const ushort* Kh = Kws + (size_t)bh * S_LEN * HD;
    const ushort* Vh = Vt  + (size_t)bh * HD * S_LEN;

    const int q0 = qb * 64 + w * 16;
    const int kstart = qb * 64 - 64;

    // stage K [192][64] swizzled (linear dest, inverse-swizzled source)
#pragma unroll
    for (int i = 0; i < 6; i++) {
        const int sb = w * 384 + i * 64;
        const int s = sb + lane;
        const int row = s >> 3;
        const int g = (s & 7) ^ (row & 7);
        int rg = kstart + row;
        rg = (rg < 0) ? 0 : (rg >= S_LEN ? S_LEN - 1 : rg);
        gload16(Kh + (size_t)rg * HD + g * 8, Ks + sb * 8);
    }

    // Q fragment (B-operand of swapped QK^T)
    short8 qa[2];
#pragma unroll
    for (int kk = 0; kk < 2; kk++)
        qa[kk] = *(const short8*)(Qh + (size_t)(q0 + lr) * HD + kk * 32 + lg * 8);

    __syncthreads();   // K staged (drain); V not yet issued

    // stage V^T [64][192] swizzled — async; drains at the second barrier
#pragma unroll
    for (int i = 0; i < 6; i++) {
        const int sb = w * 384 + i * 64;
        const int s = sb + lane;
        const int row = s / 24;
        const int sr = s - row * 24;
        const int cr = sr ^ (row & 7);
        int cg = kstart + cr * 8;
        cg = (cg < 0) ? 0 : (cg > S_LEN - 8 ? S_LEN - 8 : cg);
        gload16(Vh + (size_t)row * S_LEN + cg, Vs + sb * 8);
    }

    const int swz = (lr & 7) << 3;

    // QK^T swapped: lane holds q=lr, keys 16ct+4lg+r
    f32x4 sc[12];
#pragma unroll
    for (int ct = 0; ct < 12; ct++) {
        sc[ct] = f32x4{0.f, 0.f, 0.f, 0.f};
        const int base = (ct * 16 + lr) * 64;
        short8 kb0 = *(const short8*)(Ks + (base + ((0  + lg * 8) ^ swz)));
        short8 kb1 = *(const short8*)(Ks + (base + ((32 + lg * 8) ^ swz)));
        sc[ct] = __builtin_amdgcn_mfma_f32_16x16x32_bf16(kb0, qa[0], sc[ct], 0, 0, 0);
        sc[ct] = __builtin_amdgcn_mfma_f32_16x16x32_bf16(kb1, qa[1], sc[ct], 0, 0, 0);
    }

    // softmax: lane-local over 48 keys + 2 shfls; deferred normalization
    const float scale2 = 0.18033688f;   // (1/8) * log2(e)
    const int qi = q0 + lr;
    float sum = 0.f;
#pragma unroll
    for (int ct = 0; ct < 12; ct++) {
#pragma unroll
        for (int r = 0; r < 4; r++) {
            const int j = kstart + ct * 16 + 4 * lg + r;
            const bool valid = (j >= 0) && (j < S_LEN) && (qi - j <= 64) && (j - qi <= 64);
            const float p = valid ? exp2f(sc[ct][r] * scale2) : 0.f;
            sc[ct][r] = p;
            sum += p;
        }
    }
    sum += __shfl_xor(sum, 16);
    sum += __shfl_xor(sum, 32);
    const float inv = 1.0f / sum;

    // pack P^T: pb[ct] is the 16x16x16 B-fragment (k=4lg+j)
    s16x4 pb[12];
#pragma unroll
    for (int ct = 0; ct < 12; ct++) {
        pb[ct][0] = (short)f2bf(sc[ct][0]);
        pb[ct][1] = (short)f2bf(sc[ct][1]);
        pb[ct][2] = (short)f2bf(sc[ct][2]);
        pb[ct][3] = (short)f2bf(sc[ct][3]);
    }

    __syncthreads();   // V staged

    // PV: out^T[d][q]
    f32x4 po[4] = {};
#pragma unroll
    for (int ct = 0; ct < 12; ct++) {
        const int k0 = ct * 16 + 4 * lg;
        const int sub = k0 & 7;
        const int ch = k0 >> 3;
#pragma unroll
        for (int n = 0; n < 4; n++) {
            const int d = 16 * n + lr;
            s16x4 va = *(const s16x4*)(Vs + d * 192 + 8 * (ch ^ (lr & 7)) + sub);
            po[n] = mfma16(va, pb[ct], po[n]);
        }
    }

    const int b = bh >> 3, h = bh & 7;
    ushort* aorow = AO + ((size_t)(b * S_LEN + q0 + lr)) * DM + h * HD;
#pragma unroll
    for (int n = 0; n < 4; n++) {
        uint2 u;
        u.x = (uint)f2bf(po[n][0] * inv) | ((uint)f2bf(po[n][1] * inv) << 16);
        u.y = (uint)f2bf(po[n][2] * inv) | ((uint)f2bf(po[n][3] * inv) << 16);
        *(uint2*)(aorow + 16 * n + 4 * lg) = u;
    }
}

// ---------------------------------------------------------------------------
// Output projection (round-10): 64x128 tile, grid 512 (2 blocks/CU),
// XCD-swizzled. bf16 in via global_load_lds, f32 out.
// ---------------------------------------------------------------------------
__global__ __launch_bounds__(256) void out_proj_kernel(
    const ushort* __restrict__ AO, const ushort* __restrict__ Wo,
    const float* __restrict__ bo, float* __restrict__ Out)
{
    __shared__ __align__(1024) ushort As[64 * 64];
    __shared__ __align__(1024) ushort Bs[128 * 64];

    const int lane = threadIdx.x & 63;
    const int w    = threadIdx.x >> 6;
    const int xcd  = blockIdx.x & 7;
    const int idx  = blockIdx.x >> 3;
    const int tr   = xcd + 8 * (idx >> 2);
    const int tc   = idx & 3;
    const int c0   = tc * 128;
    const int r0   = tr * 64;
    const int lr = lane & 15;
    const int lg = lane >> 4;
    const int wr = w >> 1, wc = w & 1;
    const int ldrow = lane >> 3;
    const int ldcol = (lane & 7) * 8;

    f32x4 acc[2][4] = {};
    for (int ks = 0; ks < 8; ks++) {
        const int k0 = ks * 64;
        if (ks) __syncthreads();
        const ushort* gA = AO + (size_t)(r0 + ldrow) * DM + k0 + ldcol;
        const ushort* gB = Wo + (size_t)(c0 + ldrow) * DM + k0 + ldcol;
#pragma unroll
        for (int j = 0; j < 2; j++) {
            const int ch = w * 2 + j;
            gload16(gA + (size_t)ch * 8 * DM, As + ch * 512);
        }
#pragma unroll
        for (int j = 0; j < 4; j++) {
            const int ch = w * 4 + j;
            gload16(gB + (size_t)ch * 8 * DM, Bs + ch * 512);
        }
        __syncthreads();

#pragma unroll
        for (int kk = 0; kk < 2; kk++) {
            const int koff = kk * 32 + lg * 8;
            short8 a[2], b[4];
#pragma unroll
            for (int m = 0; m < 2; m++)
                a[m] = *(const short8*)(As + (wr * 32 + 16 * m + lr) * 64 + koff);
#pragma unroll
            for (int n = 0; n < 4; n++)
                b[n] = *(const short8*)(Bs + (wc * 64 + 16 * n + lr) * 64 + koff);
#pragma unroll
            for (int m = 0; m < 2; m++)
#pragma unroll
                for (int n = 0; n < 4; n++)
                    acc[m][n] = __builtin_amdgcn_mfma_f32_16x16x32_bf16(a[m], b[n], acc[m][n], 0, 0, 0);
        }
    }

#pragma unroll
    for (int n = 0; n < 4; n++) {
        const int c = c0 + wc * 64 + 16 * n + lr;
        const float bb = bo[c];
#pragma unroll
        for (int m = 0; m < 2; m++) {
#pragma unroll
            for (int r = 0; r < 4; r++) {
                const int row = r0 + wr * 32 + 16 * m + 4 * lg + r;
                Out[(size_t)row * DM + c] = acc[m][n][r] + bb;
            }
        }
    }
}

extern "C" void kernel_launch(void* const* d_in, const int* in_sizes, int n_in,
                              void* d_out, int out_size, void* d_ws, size_t ws_size,
                              hipStream_t stream) {
    const float* x  = (const float*)d_in[0];
    const float* Wq = (const float*)d_in[1];
    const float* bq = (const float*)d_in[2];
    const float* Wk = (const float*)d_in[3];
    const float* bk = (const float*)d_in[4];
    const float* Wv = (const float*)d_in[5];
    const float* bv = (const float*)d_in[6];
    const float* Wo = (const float*)d_in[7];
    const float* bo = (const float*)d_in[8];
    float* out = (float*)d_out;

    const size_t XE = (size_t)NB * S_LEN * DM;   // 4,194,304
    const size_t WE = (size_t)DM * DM;           // 262,144

    ushort* Xb  = (ushort*)d_ws;
    ushort* Wqb = Xb + XE;
    ushort* Wkb = Wqb + WE;
    ushort* Wvb = Wkb + WE;
    ushort* Wob = Wvb + WE;
    ushort* Qws = Wob + WE;
    ushort* Kws = Qws + XE;
    ushort* Vt  = Kws + XE;
    ushort* AO  = Vt + XE;

    cvt_all_kernel<<<2560, 256, 0, stream>>>(x, Wq, Wk, Wv, Wo, Xb, Wqb, Wkb, Wvb, Wob);
    qkv_proj_kernel<<<512, 256, 0, stream>>>(Xb, Wqb, bq, Wkb, bk, Wvb, bv, Qws, Kws, Vt);
    attn_kernel<<<1024, 256, 0, stream>>>(Qws, Kws, Vt, AO);
    out_proj_kernel<<<512, 256, 0, stream>>>(AO, Wob, bo, out);
}